// Round 2
// baseline (408.094 us; speedup 1.0000x reference)
//
#include <hip/hip_runtime.h>
#include <hip/hip_bf16.h>

typedef unsigned short u16;
typedef unsigned int u32;

constexpr int B_ = 8, T_ = 512, C_ = 1024, H_ = 16, E_ = 64, L_ = 2048;
constexpr int S_ = L_ + T_;  // 2560 merged KV length

typedef __bf16 bf16x8 __attribute__((ext_vector_type(8)));
typedef float f32x4 __attribute__((ext_vector_type(4)));
typedef float f32x16 __attribute__((ext_vector_type(16)));

// 0.125 * log2(e): folds 1/sqrt(E) and the exp->exp2 base change into q
#define QSCALE 0.18033688011112042f

__device__ inline u16 f2bf(float f) {
  u32 u = __float_as_uint(f);
  u32 r = (u + 0x7fffu + ((u >> 16) & 1u)) >> 16;
  return (u16)r;
}

// packed f32x2 -> bf16x2 (RNE), hw v_cvt_pk where available
__device__ inline u32 pk2(float a, float b) {
  union { __hip_bfloat162 h; u32 u; } cv;
  cv.h = __float22bfloat162_rn(float2{a, b});
  return cv.u;
}

// permlane32_swap: a' = concat(a[0:31], b[0:31]); b' = concat(a[32:63], b[32:63])
__device__ inline void pl32swap(u32& a, u32& b) {
  asm("v_permlane32_swap_b32 %0, %1" : "+v"(a), "+v"(b));
}

// async global->LDS, 16B per lane; lds base must be wave-uniform
__device__ inline void gload_lds16(const u16* g, u16* l) {
  __builtin_amdgcn_global_load_lds(
      (const __attribute__((address_space(1))) u32*)g,
      (__attribute__((address_space(3))) u32*)l, 16, 0, 0);
}

// ---------------- x (f32) -> bf16, 8 elements/thread -------------------------
__global__ __launch_bounds__(256) void convert_f32_bf16(const float* __restrict__ in,
                                                        u16* __restrict__ out) {
  const int i = blockIdx.x * 256 + threadIdx.x;
  const float4 a0 = ((const float4*)in)[i * 2];
  const float4 a1 = ((const float4*)in)[i * 2 + 1];
  uint4 p;
  p.x = pk2(a0.x, a0.y);
  p.y = pk2(a0.z, a0.w);
  p.z = pk2(a1.x, a1.y);
  p.w = pk2(a1.z, a1.w);
  ((uint4*)out)[i] = p;
}

// ------- transpose + downcast: in f32 (R x Ccols) -> out bf16 (Ccols x R) ----
__global__ __launch_bounds__(256) void transpose_f32_bf16(const float* __restrict__ in,
                                                          u16* __restrict__ out,
                                                          int R, int Ccols) {
  __shared__ u16 tile[64][65];
  const int r0 = blockIdx.y * 64;
  const int c0 = blockIdx.x * 64;
  const int tr = threadIdx.x >> 6;  // 0..3
  const int tc = threadIdx.x & 63;
#pragma unroll
  for (int i = 0; i < 16; ++i)
    tile[tr + i * 4][tc] = f2bf(in[(size_t)(r0 + tr + i * 4) * Ccols + c0 + tc]);
  __syncthreads();
#pragma unroll
  for (int i = 0; i < 16; ++i)
    out[(size_t)(c0 + tr + i * 4) * R + r0 + tc] = tile[tc][tr + i * 4];
}

// ---- prep: f32 KV cache -> merged bf16 Km[b,h,s,e] and Vtm[b,h,e,s] (s<L) ---
__global__ __launch_bounds__(256) void prep_kv(const float* __restrict__ kc,
                                               const float* __restrict__ vc,
                                               u16* __restrict__ Km,
                                               u16* __restrict__ Vtm) {
  __shared__ u16 vt[64 * 72];
  const int s0 = (blockIdx.x & 31) * 64;
  const int bh = blockIdx.x >> 5;
  const int tid = threadIdx.x;
  const int srow = tid >> 2;
  const int eq = (tid & 3) * 16;

  {
    const float* kp = kc + ((size_t)bh * L_ + s0 + srow) * E_ + eq;
    float kv[16];
    *(float4*)(kv + 0) = *(const float4*)(kp + 0);
    *(float4*)(kv + 4) = *(const float4*)(kp + 4);
    *(float4*)(kv + 8) = *(const float4*)(kp + 8);
    *(float4*)(kv + 12) = *(const float4*)(kp + 12);
    uint4 p0, p1;
    p0.x = pk2(kv[0], kv[1]);
    p0.y = pk2(kv[2], kv[3]);
    p0.z = pk2(kv[4], kv[5]);
    p0.w = pk2(kv[6], kv[7]);
    p1.x = pk2(kv[8], kv[9]);
    p1.y = pk2(kv[10], kv[11]);
    p1.z = pk2(kv[12], kv[13]);
    p1.w = pk2(kv[14], kv[15]);
    u16* kd = Km + ((size_t)bh * S_ + s0 + srow) * E_ + eq;
    *(uint4*)kd = p0;
    *(uint4*)(kd + 8) = p1;
  }
  {
    const float* vp = vc + ((size_t)bh * L_ + s0 + srow) * E_ + eq;
    float vv[16];
    *(float4*)(vv + 0) = *(const float4*)(vp + 0);
    *(float4*)(vv + 4) = *(const float4*)(vp + 4);
    *(float4*)(vv + 8) = *(const float4*)(vp + 8);
    *(float4*)(vv + 12) = *(const float4*)(vp + 12);
    uint4 p0, p1;
    p0.x = pk2(vv[0], vv[1]);
    p0.y = pk2(vv[2], vv[3]);
    p0.z = pk2(vv[4], vv[5]);
    p0.w = pk2(vv[6], vv[7]);
    p1.x = pk2(vv[8], vv[9]);
    p1.y = pk2(vv[10], vv[11]);
    p1.z = pk2(vv[12], vv[13]);
    p1.w = pk2(vv[14], vv[15]);
    *(uint4*)(vt + srow * 72 + eq) = p0;
    *(uint4*)(vt + srow * 72 + eq + 8) = p1;
  }
  __syncthreads();
  {
    const int erow = tid >> 2;
    const int sq = (tid & 3) * 16;
    u16 o[16];
#pragma unroll
    for (int j = 0; j < 16; ++j) o[j] = vt[(sq + j) * 72 + erow];
    u16* vd = Vtm + ((size_t)bh * E_ + erow) * S_ + s0 + sq;
    *(uint4*)vd = *(uint4*)(o + 0);
    *(uint4*)(vd + 8) = *(uint4*)(o + 8);
  }
}

// ---- vtrans: new-v bf16 row-major vh[bh,t,e] -> Vtm[bh,e,L+t] ---------------
__global__ __launch_bounds__(256) void vtrans(const u16* __restrict__ vh,
                                              u16* __restrict__ Vtm) {
  __shared__ u16 vt[64 * 72];
  const int t0 = (blockIdx.x & 7) * 64;
  const int bh = blockIdx.x >> 3;
  const int tid = threadIdx.x;
  const int srow = tid >> 2;
  const int eq = (tid & 3) * 16;
  const u16* vp = vh + ((size_t)bh * T_ + t0 + srow) * E_ + eq;
  *(uint4*)(vt + srow * 72 + eq) = *(const uint4*)vp;
  *(uint4*)(vt + srow * 72 + eq + 8) = *(const uint4*)(vp + 8);
  __syncthreads();
  const int erow = tid >> 2;
  const int sq = (tid & 3) * 16;
  u16 o[16];
#pragma unroll
  for (int j = 0; j < 16; ++j) o[j] = vt[(sq + j) * 72 + erow];
  u16* vd = Vtm + ((size_t)bh * E_ + erow) * S_ + L_ + t0 + sq;
  *(uint4*)vd = *(uint4*)(o + 0);
  *(uint4*)(vd + 8) = *(uint4*)(o + 8);
}

// --------- m97-style GEMM: C[M,N] = A[M,K] @ BT[N,K]^T + bias[n] -------------
// 128x128 tile, BK=32, global_load_lds staging, 4 waves each 64x64.
// MODE 0: scatter qkv: q (xQSCALE) -> qh[b,h,t,e]; k -> Km[..,L+t,e];
//         v -> vout[b,h,t,e] row-major (transposed later by vtrans)
// MODE 1: f32 row-major store to outf
template <int MODE>
__global__ __launch_bounds__(256) void gemm128(const u16* __restrict__ A,
                                               const u16* __restrict__ BT,
                                               const float* __restrict__ bias,
                                               u16* __restrict__ qh,
                                               u16* __restrict__ Km,
                                               u16* __restrict__ vout,
                                               float* __restrict__ outf,
                                               int M, int N, int K) {
  __shared__ __align__(16) u16 As[128 * 32];
  __shared__ __align__(16) u16 Bs[128 * 32];
  const int tid = threadIdx.x;
  const int lane = tid & 63;
  const int w = tid >> 6;
  const int m0 = blockIdx.y * 128;
  const int n0 = blockIdx.x * 128;
  const int wm = (w >> 1) * 64;
  const int wn = (w & 1) * 64;
  const int fm = lane & 15;
  const int fk = (lane >> 4) * 8;

  // staging: wave w covers rows [w*16, w*16+16) and +64; lane l -> row l>>2, col (l&3)*8
  const int srow = w * 16 + (lane >> 2);
  const int scol = (lane & 3) * 8;
  const u16* Ag = A + (size_t)(m0 + srow) * K + scol;
  const u16* Bg = BT + (size_t)(n0 + srow) * K + scol;
  u16* AsU = As + w * 512;  // wave-uniform LDS bases (u16 units)
  u16* BsU = Bs + w * 512;

  f32x4 acc[4][4];
#pragma unroll
  for (int i = 0; i < 4; ++i)
#pragma unroll
    for (int j = 0; j < 4; ++j) acc[i][j] = f32x4{0.f, 0.f, 0.f, 0.f};

  for (int k0 = 0; k0 < K; k0 += 32) {
    gload_lds16(Ag, AsU);
    gload_lds16(Ag + (size_t)64 * K, AsU + 2048);
    gload_lds16(Bg, BsU);
    gload_lds16(Bg + (size_t)64 * K, BsU + 2048);
    Ag += 32;
    Bg += 32;
    __syncthreads();
    bf16x8 af[4], bf[4];
#pragma unroll
    for (int i = 0; i < 4; ++i)
      af[i] = *(const bf16x8*)(As + (wm + i * 16 + fm) * 32 + fk);
#pragma unroll
    for (int j = 0; j < 4; ++j)
      bf[j] = *(const bf16x8*)(Bs + (wn + j * 16 + fm) * 32 + fk);
#pragma unroll
    for (int i = 0; i < 4; ++i)
#pragma unroll
      for (int j = 0; j < 4; ++j)
        acc[i][j] = __builtin_amdgcn_mfma_f32_16x16x32_bf16(af[i], bf[j], acc[i][j], 0, 0, 0);
    __syncthreads();
  }

  const int rbase = (lane >> 4) * 4;
  const int cbase = lane & 15;
#pragma unroll
  for (int i = 0; i < 4; ++i)
#pragma unroll
    for (int j = 0; j < 4; ++j) {
      const int n = n0 + wn + j * 16 + cbase;
      const float bv = bias[n];
#pragma unroll
      for (int r = 0; r < 4; ++r) {
        const int m = m0 + wm + i * 16 + rbase + r;
        const float v = acc[i][j][r] + bv;
        if (MODE == 0) {
          const int seg = n >> 10;  // 0:q 1:k 2:v
          const int c = n & 1023;
          const int e = c & 63;
          const int bhh = ((m >> 9) * H_) + (c >> 6);
          const int t = m & 511;
          if (seg == 0)
            qh[((size_t)bhh * T_ + t) * E_ + e] = f2bf(v * QSCALE);
          else if (seg == 1)
            Km[((size_t)bhh * S_ + L_ + t) * E_ + e] = f2bf(v);
          else
            vout[((size_t)bhh * T_ + t) * E_ + e] = f2bf(v);
        } else {
          outf[(size_t)m * N + n] = v;
        }
      }
    }
}

// ----- MFMA flash attention v5: barrier-free, LDS-free, direct global loads --
// K/V are L2/L3-resident (655KB per bh) -> no LDS staging (pure overhead).
// Each wave owns 32 q rows, iterates only its causally-needed 64-key chunks.
// Swapped S^T = mfma(K,Q); in-register softmax via cvt_pk + permlane32_swap;
// l via ones-MFMA. 2-deep K ping-pong + early-issued V loads hide L2 latency.
#define ATTN_CHUNK(KF, KN, cc)                                                   \
  {                                                                              \
    const int sbase = (cc) << 6;                                                 \
    const int cpf = ((cc) + 1 < nck) ? (cc) + 1 : nck - 1;                       \
    bf16x8 vf[2][4];                                                             \
    _Pragma("unroll") for (int eb = 0; eb < 2; ++eb)                             \
      _Pragma("unroll") for (int t = 0; t < 4; ++t)                              \
        vf[eb][t] = *(const bf16x8*)(Vl + (size_t)eb * 32 * S_ + (cc) * 64 + t * 16); \
    bf16x8 pa[4];                                                                \
    _Pragma("unroll") for (int kb = 0; kb < 2; ++kb) {                           \
      f32x16 s;                                                                  \
      _Pragma("unroll") for (int i = 0; i < 16; ++i) s[i] = 0.f;                 \
      _Pragma("unroll") for (int et = 0; et < 4; ++et)                           \
        s = __builtin_amdgcn_mfma_f32_32x32x16_bf16(KF[kb][et], qf[et], s, 0, 0, 0); \
      if ((cc) == nck - 1) {                                                     \
        const int mb = sbase + kb * 32 + hi * 4;                                 \
        _Pragma("unroll") for (int r = 0; r < 16; ++r) {                         \
          const int keypos = mb + (r & 3) + 8 * (r >> 2);                        \
          if (keypos > qpos) s[r] = -1e30f;                                      \
        }                                                                        \
      }                                                                          \
      _Pragma("unroll") for (int r = 0; r < 16; ++r) s[r] = exp2f(s[r]);         \
      _Pragma("unroll") for (int t = 0; t < 2; ++t) {                            \
        u32 x0 = pk2(s[8 * t + 0], s[8 * t + 1]);                                \
        u32 y0 = pk2(s[8 * t + 4], s[8 * t + 5]);                                \
        u32 x1 = pk2(s[8 * t + 2], s[8 * t + 3]);                                \
        u32 y1 = pk2(s[8 * t + 6], s[8 * t + 7]);                                \
        pl32swap(x0, y0);                                                        \
        pl32swap(x1, y1);                                                        \
        union { u32 u[4]; bf16x8 v; } pu;                                        \
        pu.u[0] = x0;                                                            \
        pu.u[1] = x1;                                                            \
        pu.u[2] = y0;                                                            \
        pu.u[3] = y1;                                                            \
        pa[kb * 2 + t] = pu.v;                                                   \
      }                                                                          \
    }                                                                            \
    _Pragma("unroll") for (int kb = 0; kb < 2; ++kb)                             \
      _Pragma("unroll") for (int et = 0; et < 4; ++et)                           \
        KN[kb][et] = *(const bf16x8*)(Kl + ((size_t)cpf * 64 + kb * 32) * E_ + et * 16); \
    _Pragma("unroll") for (int t = 0; t < 4; ++t)                                \
      lacc = __builtin_amdgcn_mfma_f32_32x32x16_bf16(ones, pa[t], lacc, 0, 0, 0); \
    _Pragma("unroll") for (int t = 0; t < 4; ++t)                                \
      Yt[0] = __builtin_amdgcn_mfma_f32_32x32x16_bf16(vf[0][t], pa[t], Yt[0], 0, 0, 0); \
    _Pragma("unroll") for (int t = 0; t < 4; ++t)                                \
      Yt[1] = __builtin_amdgcn_mfma_f32_32x32x16_bf16(vf[1][t], pa[t], Yt[1], 0, 0, 0); \
  }

__global__ __launch_bounds__(256, 2) void attn_v5(const u16* __restrict__ qh,
                                                  const u16* __restrict__ Km,
                                                  const u16* __restrict__ Vtm,
                                                  u16* __restrict__ y2) {
  const int tid = threadIdx.x;
  const int lane = tid & 63;
  const int w = tid >> 6;
  const int bh = blockIdx.x & 127;  // same-bh blocks 128 apart
  const int qt = blockIdx.x >> 7;
  const int h = bh & (H_ - 1);
  const int b = bh >> 4;
  const int t0 = qt * 128;

  const int ln = lane & 31;
  const int hi = lane >> 5;

  // ---- Q fragments (B-operand): lane holds Q[q=ln][e = et*16 + hi*8 + j]
  const u16* qbase = qh + ((size_t)bh * T_ + t0 + w * 32 + ln) * E_;
  bf16x8 qf[4];
#pragma unroll
  for (int et = 0; et < 4; ++et)
    qf[et] = *(const bf16x8*)(qbase + et * 16 + hi * 8);

  const int qmin = L_ + t0 + w * 32;      // global pos of this wave's first q
  const int qpos = qmin + ln;             // this lane's q position
  const int nck = (qmin + 32 + 63) >> 6;  // chunks this wave actually needs

  // per-lane fragment base pointers (16B-aligned)
  const u16* Kl = Km + ((size_t)bh * S_ + ln) * E_ + hi * 8;
  const u16* Vl = Vtm + ((size_t)bh * E_ + ln) * S_ + hi * 8;

  f32x16 Yt[2], lacc;
#pragma unroll
  for (int i = 0; i < 16; ++i) {
    Yt[0][i] = 0.f;
    Yt[1][i] = 0.f;
    lacc[i] = 0.f;
  }

  const bf16x8 ones = {(__bf16)1.f, (__bf16)1.f, (__bf16)1.f, (__bf16)1.f,
                       (__bf16)1.f, (__bf16)1.f, (__bf16)1.f, (__bf16)1.f};

  // ---- prologue: load chunk 0's K fragments
  bf16x8 kA[2][4], kB[2][4];
#pragma unroll
  for (int kb = 0; kb < 2; ++kb)
#pragma unroll
    for (int et = 0; et < 4; ++et)
      kA[kb][et] = *(const bf16x8*)(Kl + (size_t)(kb * 32) * E_ + et * 16);

  int c = 0;
  while (true) {
    ATTN_CHUNK(kA, kB, c);
    if (++c >= nck) break;
    ATTN_CHUNK(kB, kA, c);
    if (++c >= nck) break;
  }

  // ---- epilogue: lane holds q = ln; e = 32*eb + 8*(r>>2) + 4*hi + (r&3)
  const float rl = 1.f / lacc[0];
  const int t_out = t0 + w * 32 + ln;
  u16* yp = y2 + ((size_t)b * T_ + t_out) * C_ + h * E_ + hi * 4;
#pragma unroll
  for (int eb = 0; eb < 2; ++eb)
#pragma unroll
    for (int g = 0; g < 4; ++g) {
      uint2 st;
      st.x = pk2(Yt[eb][4 * g + 0] * rl, Yt[eb][4 * g + 1] * rl);
      st.y = pk2(Yt[eb][4 * g + 2] * rl, Yt[eb][4 * g + 3] * rl);
      *(uint2*)(yp + eb * 32 + g * 8) = st;
    }
}

// ---------------- launch -----------------------------------------------------
extern "C" void kernel_launch(void* const* d_in, const int* in_sizes, int n_in,
                              void* d_out, int out_size, void* d_ws, size_t ws_size,
                              hipStream_t stream) {
  const float* x = (const float*)d_in[0];
  const float* kc = (const float*)d_in[1];
  const float* vc = (const float*)d_in[2];
  const float* Wqkv = (const float*)d_in[3];
  const float* bqkv = (const float*)d_in[4];
  const float* Wproj = (const float*)d_in[5];
  const float* bproj = (const float*)d_in[6];
  float* out = (float*)d_out;

  u16* qh = (u16*)d_ws;                  // 4194304
  u16* y2 = qh + 4194304;                // 4194304 (also scratch for new-v rows)
  u16* xb = y2 + 4194304;                // 4194304
  u16* WqT = xb + 4194304;               // 3145728
  u16* WpT = WqT + 3145728;              // 1048576
  u16* Km = WpT + 1048576;               // 20971520
  u16* Vtm = Km + 20971520;              // 20971520

  convert_f32_bf16<<<dim3(2048), 256, 0, stream>>>(x, xb);
  transpose_f32_bf16<<<dim3(48, 16), 256, 0, stream>>>(Wqkv, WqT, 1024, 3072);
  transpose_f32_bf16<<<dim3(16, 16), 256, 0, stream>>>(Wproj, WpT, 1024, 1024);
  prep_kv<<<dim3(128 * 32), 256, 0, stream>>>(kc, vc, Km, Vtm);

  // qkv = x @ Wqkv + bqkv -> qh (xQSCALE), Km[:, L:], v rows -> y2 scratch
  gemm128<0><<<dim3(24, 32), 256, 0, stream>>>(xb, WqT, bqkv, qh, Km, y2, nullptr,
                                               4096, 3072, 1024);
  vtrans<<<dim3(128 * 8), 256, 0, stream>>>(y2, Vtm);

  attn_v5<<<dim3(512), 256, 0, stream>>>(qh, Km, Vtm, y2);

  // out = y @ Wproj + bproj (f32 out)
  gemm128<1><<<dim3(8, 32), 256, 0, stream>>>(y2, WpT, bproj, nullptr, nullptr,
                                              nullptr, out, 4096, 1024, 1024);
}

// Round 3
// 355.354 us; speedup vs baseline: 1.1484x; 1.1484x over previous
//
#include <hip/hip_runtime.h>
#include <hip/hip_bf16.h>

typedef unsigned short u16;
typedef unsigned int u32;

constexpr int B_ = 8, T_ = 512, C_ = 1024, H_ = 16, E_ = 64, L_ = 2048;
constexpr int S_ = L_ + T_;  // 2560 merged KV length

typedef __bf16 bf16x8 __attribute__((ext_vector_type(8)));
typedef float f32x4 __attribute__((ext_vector_type(4)));
typedef float f32x16 __attribute__((ext_vector_type(16)));

// 0.125 * log2(e): folds 1/sqrt(E) and the exp->exp2 base change into q
#define QSCALE 0.18033688011112042f

__device__ inline u16 f2bf(float f) {
  u32 u = __float_as_uint(f);
  u32 r = (u + 0x7fffu + ((u >> 16) & 1u)) >> 16;
  return (u16)r;
}

// packed f32x2 -> bf16x2 (RNE), hw v_cvt_pk where available
__device__ inline u32 pk2(float a, float b) {
  union { __hip_bfloat162 h; u32 u; } cv;
  cv.h = __float22bfloat162_rn(float2{a, b});
  return cv.u;
}

// permlane32_swap: a' = concat(a[0:31], b[0:31]); b' = concat(a[32:63], b[32:63])
__device__ inline void pl32swap(u32& a, u32& b) {
  asm("v_permlane32_swap_b32 %0, %1" : "+v"(a), "+v"(b));
}

// async global->LDS, 16B per lane; lds base must be wave-uniform
__device__ inline void gload_lds16(const u16* g, u16* l) {
  __builtin_amdgcn_global_load_lds(
      (const __attribute__((address_space(1))) u32*)g,
      (__attribute__((address_space(3))) u32*)l, 16, 0, 0);
}

// ---------------- x (f32) -> bf16, 8 elements/thread -------------------------
__global__ __launch_bounds__(256) void convert_f32_bf16(const float* __restrict__ in,
                                                        u16* __restrict__ out) {
  const int i = blockIdx.x * 256 + threadIdx.x;
  const float4 a0 = ((const float4*)in)[i * 2];
  const float4 a1 = ((const float4*)in)[i * 2 + 1];
  uint4 p;
  p.x = pk2(a0.x, a0.y);
  p.y = pk2(a0.z, a0.w);
  p.z = pk2(a1.x, a1.y);
  p.w = pk2(a1.z, a1.w);
  ((uint4*)out)[i] = p;
}

// ------- transpose + downcast: in f32 (R x Ccols) -> out bf16 (Ccols x R) ----
__global__ __launch_bounds__(256) void transpose_f32_bf16(const float* __restrict__ in,
                                                          u16* __restrict__ out,
                                                          int R, int Ccols) {
  __shared__ u16 tile[64][65];
  const int r0 = blockIdx.y * 64;
  const int c0 = blockIdx.x * 64;
  const int tr = threadIdx.x >> 6;  // 0..3
  const int tc = threadIdx.x & 63;
#pragma unroll
  for (int i = 0; i < 16; ++i)
    tile[tr + i * 4][tc] = f2bf(in[(size_t)(r0 + tr + i * 4) * Ccols + c0 + tc]);
  __syncthreads();
#pragma unroll
  for (int i = 0; i < 16; ++i)
    out[(size_t)(c0 + tr + i * 4) * R + r0 + tc] = tile[tc][tr + i * 4];
}

// ---- prep: f32 KV cache -> merged bf16 Km[b,h,s,e] and Vtm[b,h,e,s] (s<L) ---
__global__ __launch_bounds__(256) void prep_kv(const float* __restrict__ kc,
                                               const float* __restrict__ vc,
                                               u16* __restrict__ Km,
                                               u16* __restrict__ Vtm) {
  __shared__ u16 vt[64 * 72];
  const int s0 = (blockIdx.x & 31) * 64;
  const int bh = blockIdx.x >> 5;
  const int tid = threadIdx.x;
  const int srow = tid >> 2;
  const int eq = (tid & 3) * 16;

  {
    const float* kp = kc + ((size_t)bh * L_ + s0 + srow) * E_ + eq;
    float kv[16];
    *(float4*)(kv + 0) = *(const float4*)(kp + 0);
    *(float4*)(kv + 4) = *(const float4*)(kp + 4);
    *(float4*)(kv + 8) = *(const float4*)(kp + 8);
    *(float4*)(kv + 12) = *(const float4*)(kp + 12);
    uint4 p0, p1;
    p0.x = pk2(kv[0], kv[1]);
    p0.y = pk2(kv[2], kv[3]);
    p0.z = pk2(kv[4], kv[5]);
    p0.w = pk2(kv[6], kv[7]);
    p1.x = pk2(kv[8], kv[9]);
    p1.y = pk2(kv[10], kv[11]);
    p1.z = pk2(kv[12], kv[13]);
    p1.w = pk2(kv[14], kv[15]);
    u16* kd = Km + ((size_t)bh * S_ + s0 + srow) * E_ + eq;
    *(uint4*)kd = p0;
    *(uint4*)(kd + 8) = p1;
  }
  {
    const float* vp = vc + ((size_t)bh * L_ + s0 + srow) * E_ + eq;
    float vv[16];
    *(float4*)(vv + 0) = *(const float4*)(vp + 0);
    *(float4*)(vv + 4) = *(const float4*)(vp + 4);
    *(float4*)(vv + 8) = *(const float4*)(vp + 8);
    *(float4*)(vv + 12) = *(const float4*)(vp + 12);
    uint4 p0, p1;
    p0.x = pk2(vv[0], vv[1]);
    p0.y = pk2(vv[2], vv[3]);
    p0.z = pk2(vv[4], vv[5]);
    p0.w = pk2(vv[6], vv[7]);
    p1.x = pk2(vv[8], vv[9]);
    p1.y = pk2(vv[10], vv[11]);
    p1.z = pk2(vv[12], vv[13]);
    p1.w = pk2(vv[14], vv[15]);
    *(uint4*)(vt + srow * 72 + eq) = p0;
    *(uint4*)(vt + srow * 72 + eq + 8) = p1;
  }
  __syncthreads();
  {
    const int erow = tid >> 2;
    const int sq = (tid & 3) * 16;
    u16 o[16];
#pragma unroll
    for (int j = 0; j < 16; ++j) o[j] = vt[(sq + j) * 72 + erow];
    u16* vd = Vtm + ((size_t)bh * E_ + erow) * S_ + s0 + sq;
    *(uint4*)vd = *(uint4*)(o + 0);
    *(uint4*)(vd + 8) = *(uint4*)(o + 8);
  }
}

// ---- vtrans: new-v bf16 row-major vh[bh,t,e] -> Vtm[bh,e,L+t] ---------------
__global__ __launch_bounds__(256) void vtrans(const u16* __restrict__ vh,
                                              u16* __restrict__ Vtm) {
  __shared__ u16 vt[64 * 72];
  const int t0 = (blockIdx.x & 7) * 64;
  const int bh = blockIdx.x >> 3;
  const int tid = threadIdx.x;
  const int srow = tid >> 2;
  const int eq = (tid & 3) * 16;
  const u16* vp = vh + ((size_t)bh * T_ + t0 + srow) * E_ + eq;
  *(uint4*)(vt + srow * 72 + eq) = *(const uint4*)vp;
  *(uint4*)(vt + srow * 72 + eq + 8) = *(const uint4*)(vp + 8);
  __syncthreads();
  const int erow = tid >> 2;
  const int sq = (tid & 3) * 16;
  u16 o[16];
#pragma unroll
  for (int j = 0; j < 16; ++j) o[j] = vt[(sq + j) * 72 + erow];
  u16* vd = Vtm + ((size_t)bh * E_ + erow) * S_ + L_ + t0 + sq;
  *(uint4*)vd = *(uint4*)(o + 0);
  *(uint4*)(vd + 8) = *(uint4*)(o + 8);
}

// --------- m97-style GEMM: C[M,N] = A[M,K] @ BT[N,K]^T + bias[n] -------------
// 128x128 tile, BK=32, global_load_lds staging, 4 waves each 64x64.
// MODE 0: scatter qkv: q (xQSCALE) -> qh[b,h,t,e]; k -> Km[..,L+t,e];
//         v -> vout[b,h,t,e] row-major (transposed later by vtrans)
// MODE 1: f32 row-major store to outf
template <int MODE>
__global__ __launch_bounds__(256) void gemm128(const u16* __restrict__ A,
                                               const u16* __restrict__ BT,
                                               const float* __restrict__ bias,
                                               u16* __restrict__ qh,
                                               u16* __restrict__ Km,
                                               u16* __restrict__ vout,
                                               float* __restrict__ outf,
                                               int M, int N, int K) {
  __shared__ __align__(16) u16 As[128 * 32];
  __shared__ __align__(16) u16 Bs[128 * 32];
  const int tid = threadIdx.x;
  const int lane = tid & 63;
  const int w = tid >> 6;
  const int m0 = blockIdx.y * 128;
  const int n0 = blockIdx.x * 128;
  const int wm = (w >> 1) * 64;
  const int wn = (w & 1) * 64;
  const int fm = lane & 15;
  const int fk = (lane >> 4) * 8;

  // staging: wave w covers rows [w*16, w*16+16) and +64; lane l -> row l>>2, col (l&3)*8
  const int srow = w * 16 + (lane >> 2);
  const int scol = (lane & 3) * 8;
  const u16* Ag = A + (size_t)(m0 + srow) * K + scol;
  const u16* Bg = BT + (size_t)(n0 + srow) * K + scol;
  u16* AsU = As + w * 512;  // wave-uniform LDS bases (u16 units)
  u16* BsU = Bs + w * 512;

  f32x4 acc[4][4];
#pragma unroll
  for (int i = 0; i < 4; ++i)
#pragma unroll
    for (int j = 0; j < 4; ++j) acc[i][j] = f32x4{0.f, 0.f, 0.f, 0.f};

  for (int k0 = 0; k0 < K; k0 += 32) {
    gload_lds16(Ag, AsU);
    gload_lds16(Ag + (size_t)64 * K, AsU + 2048);
    gload_lds16(Bg, BsU);
    gload_lds16(Bg + (size_t)64 * K, BsU + 2048);
    Ag += 32;
    Bg += 32;
    __syncthreads();
    bf16x8 af[4], bf[4];
#pragma unroll
    for (int i = 0; i < 4; ++i)
      af[i] = *(const bf16x8*)(As + (wm + i * 16 + fm) * 32 + fk);
#pragma unroll
    for (int j = 0; j < 4; ++j)
      bf[j] = *(const bf16x8*)(Bs + (wn + j * 16 + fm) * 32 + fk);
#pragma unroll
    for (int i = 0; i < 4; ++i)
#pragma unroll
      for (int j = 0; j < 4; ++j)
        acc[i][j] = __builtin_amdgcn_mfma_f32_16x16x32_bf16(af[i], bf[j], acc[i][j], 0, 0, 0);
    __syncthreads();
  }

  const int rbase = (lane >> 4) * 4;
  const int cbase = lane & 15;
#pragma unroll
  for (int i = 0; i < 4; ++i)
#pragma unroll
    for (int j = 0; j < 4; ++j) {
      const int n = n0 + wn + j * 16 + cbase;
      const float bv = bias[n];
#pragma unroll
      for (int r = 0; r < 4; ++r) {
        const int m = m0 + wm + i * 16 + rbase + r;
        const float v = acc[i][j][r] + bv;
        if (MODE == 0) {
          const int seg = n >> 10;  // 0:q 1:k 2:v
          const int c = n & 1023;
          const int e = c & 63;
          const int bhh = ((m >> 9) * H_) + (c >> 6);
          const int t = m & 511;
          if (seg == 0)
            qh[((size_t)bhh * T_ + t) * E_ + e] = f2bf(v * QSCALE);
          else if (seg == 1)
            Km[((size_t)bhh * S_ + L_ + t) * E_ + e] = f2bf(v);
          else
            vout[((size_t)bhh * T_ + t) * E_ + e] = f2bf(v);
        } else {
          outf[(size_t)m * N + n] = v;
        }
      }
    }
}

// ----- MFMA flash attention v6: key-parity wave split, 8 waves/block ---------
// No-max softmax => (Y,l) are pure sums over keys: associative. Wave pair
// (w, w+4) owns the same 32 q rows; wave w does even 64-key chunks, w+4 odd.
// 2x resident waves (4/SIMD), one barrier per TWO chunks, same global traffic.
// LDS: 4 K-bufs + 4 V-bufs (half x parity) = 64KB; final (Y,l) add via LDS.
__global__ __launch_bounds__(512, 4) void attn_v6(const u16* __restrict__ qh,
                                                  const u16* __restrict__ Km,
                                                  const u16* __restrict__ Vtm,
                                                  u16* __restrict__ y2) {
  __shared__ __align__(16) u16 smem[32768];  // 64KB
  u16* KsB = smem;           // [half][par][64*64]
  u16* VtsB = smem + 16384;  // [half][par][64*64]

  const int tid = threadIdx.x;
  const int lane = tid & 63;
  const int w = tid >> 6;       // 0..7
  const int wq = w & 3;         // q-tile within block
  const int par = w >> 2;       // key-chunk parity this wave computes
  const int bh = blockIdx.x & 127;
  const int qt = blockIdx.x >> 7;
  const int h = bh & (H_ - 1);
  const int b = bh >> 4;
  const int t0 = qt * 128;

  const int ln = lane & 31;
  const int hi = lane >> 5;
  const int swz = ln & 7;

  // ---- Q fragments (B-operand): lane holds Q[q=ln][e = et*16 + hi*8 + j]
  const u16* qbase = qh + ((size_t)bh * T_ + t0 + wq * 32 + ln) * E_;
  bf16x8 qf[4];
#pragma unroll
  for (int et = 0; et < 4; ++et)
    qf[et] = *(const bf16x8*)(qbase + et * 16 + hi * 8);

  // ---- staging geometry: 256-thread halves; threads [sp*256, ...) stage parity sp
  const int tq = tid & 255;
  const int sp = tid >> 8;       // parity this thread stages
  const int srow = tq >> 2;      // 0..63
  const int su = (tq & 3) * 2;   // 16B units 0,2,4,6
  const u16* kg = Km + ((size_t)bh * S_ + srow) * E_ + su * 8;
  const u16* vg = Vtm + ((size_t)bh * E_ + srow) * S_ + su * 8;
  const int st0 = srow * 64 + ((su ^ (srow & 7)) * 8);
  const int st1 = srow * 64 + (((su + 1) ^ (srow & 7)) * 8);

  f32x16 Yt[2], lacc, zero16;
#pragma unroll
  for (int i = 0; i < 16; ++i) {
    Yt[0][i] = 0.f;
    Yt[1][i] = 0.f;
    lacc[i] = 0.f;
    zero16[i] = 0.f;
  }

  const bf16x8 ones = {(__bf16)1.f, (__bf16)1.f, (__bf16)1.f, (__bf16)1.f,
                       (__bf16)1.f, (__bf16)1.f, (__bf16)1.f, (__bf16)1.f};

  const int qmin_w = L_ + t0 + wq * 32;   // global pos of this wave's first q
  const int qpos = qmin_w + ln;
  const int nchunk = (L_ + t0 + 128) >> 6;  // always even (34/36/38/40)
  const int npair = nchunk >> 1;

  // ---- prologue: stage chunk pair (0,1) into half 0
  {
    const size_t ko = (size_t)sp * 64 * E_;
    const int vo = sp * 64;
    uint4 kr0 = *(const uint4*)(kg + ko);
    uint4 kr1 = *(const uint4*)(kg + ko + 8);
    uint4 vr0 = *(const uint4*)(vg + vo);
    uint4 vr1 = *(const uint4*)(vg + vo + 8);
    u16* kd = KsB + sp * 4096;
    u16* vd = VtsB + sp * 4096;
    *(uint4*)(kd + st0) = kr0;
    *(uint4*)(kd + st1) = kr1;
    *(uint4*)(vd + st0) = vr0;
    *(uint4*)(vd + st1) = vr1;
  }
  __syncthreads();

  for (int i = 0; i < npair; ++i) {
    const int hlf = i & 1;
    const int cs = 2 * (i + 1) + sp;  // chunk this thread stages
    const bool more = cs < nchunk;
    uint4 kr0, kr1, vr0, vr1;
    if (more) {  // issue early: latency hides under compute (T14)
      const size_t ko = (size_t)cs * 64 * E_;
      const int vo = cs * 64;
      kr0 = *(const uint4*)(kg + ko);
      kr1 = *(const uint4*)(kg + ko + 8);
      vr0 = *(const uint4*)(vg + vo);
      vr1 = *(const uint4*)(vg + vo + 8);
    }

    const int cmy = 2 * i + par;     // chunk this wave computes
    const int sbase = cmy << 6;
    if (sbase <= qmin_w + 31) {
      const u16* ks = KsB + (hlf * 2 + par) * 4096;
      const u16* vs = VtsB + (hlf * 2 + par) * 4096;
      bf16x8 pa[4];
#pragma unroll
      for (int kb = 0; kb < 2; ++kb) {
        // ---- S^T = K.Q^T (D: row=key_local, col=q_local); first MFMA takes zero16
        f32x16 s;
#pragma unroll
        for (int et = 0; et < 4; ++et) {
          const bf16x8 kf = *(const bf16x8*)(
              ks + (kb * 32 + ln) * 64 + (((et * 2 + hi) ^ swz) * 8));
          s = __builtin_amdgcn_mfma_f32_32x32x16_bf16(kf, qf[et],
                                                      et == 0 ? zero16 : s, 0, 0, 0);
        }

        // ---- causal mask (straddling chunks only)
        if (sbase + 63 > qmin_w) {
          const int mb = sbase + kb * 32 + hi * 4;
#pragma unroll
          for (int r = 0; r < 16; ++r) {
            const int keypos = mb + (r & 3) + 8 * (r >> 2);
            if (keypos > qpos) s[r] = -1e30f;
          }
        }

        // ---- p = exp2(s)
#pragma unroll
        for (int r = 0; r < 16; ++r) s[r] = exp2f(s[r]);

        // ---- pack to bf16 + permlane32_swap -> PV A-fragments (T12)
#pragma unroll
        for (int t = 0; t < 2; ++t) {
          u32 x0 = pk2(s[8 * t + 0], s[8 * t + 1]);
          u32 y0 = pk2(s[8 * t + 4], s[8 * t + 5]);
          u32 x1 = pk2(s[8 * t + 2], s[8 * t + 3]);
          u32 y1 = pk2(s[8 * t + 6], s[8 * t + 7]);
          pl32swap(x0, y0);
          pl32swap(x1, y1);
          union { u32 u[4]; bf16x8 v; } pu;
          pu.u[0] = x0;
          pu.u[1] = x1;
          pu.u[2] = y0;
          pu.u[3] = y1;
          pa[kb * 2 + t] = pu.v;
        }
      }

      // ---- l += P @ 1 (ones-MFMA)
#pragma unroll
      for (int t = 0; t < 4; ++t)
        lacc = __builtin_amdgcn_mfma_f32_32x32x16_bf16(ones, pa[t], lacc, 0, 0, 0);

      // ---- Y^T += V^T.P^T
#pragma unroll
      for (int eb = 0; eb < 2; ++eb)
#pragma unroll
        for (int t = 0; t < 4; ++t) {
          const bf16x8 vf = *(const bf16x8*)(
              vs + (eb * 32 + ln) * 64 + (((t * 2 + hi) ^ swz) * 8));
          Yt[eb] = __builtin_amdgcn_mfma_f32_32x32x16_bf16(vf, pa[t], Yt[eb], 0, 0, 0);
        }
    }

    // write staged pair into the other half (reads of current half are done)
    if (more) {
      u16* kd = KsB + ((hlf ^ 1) * 2 + sp) * 4096;
      u16* vd = VtsB + ((hlf ^ 1) * 2 + sp) * 4096;
      *(uint4*)(kd + st0) = kr0;
      *(uint4*)(kd + st1) = kr1;
      *(uint4*)(vd + st0) = vr0;
      *(uint4*)(vd + st1) = vr1;
    }
    __syncthreads();
  }

  // ---- cross-parity reduction: (Y,l) are pure sums
  float* red = (float*)smem;
  if (par == 1) {
    float* rp = red + ((size_t)(wq * 64 + lane)) * 34;
#pragma unroll
    for (int i = 0; i < 16; ++i) rp[i] = Yt[0][i];
#pragma unroll
    for (int i = 0; i < 16; ++i) rp[16 + i] = Yt[1][i];
    rp[32] = lacc[0];
  }
  __syncthreads();
  if (par == 0) {
    const float* rp = red + ((size_t)(wq * 64 + lane)) * 34;
#pragma unroll
    for (int i = 0; i < 16; ++i) Yt[0][i] += rp[i];
#pragma unroll
    for (int i = 0; i < 16; ++i) Yt[1][i] += rp[16 + i];
    const float rl = 1.f / (lacc[0] + rp[32]);

    // ---- epilogue: lane holds q = ln; e = 32*eb + 8*(r>>2) + 4*hi + (r&3)
    const int t_out = t0 + wq * 32 + ln;
    u16* yp = y2 + ((size_t)b * T_ + t_out) * C_ + h * E_ + hi * 4;
#pragma unroll
    for (int eb = 0; eb < 2; ++eb)
#pragma unroll
      for (int g = 0; g < 4; ++g) {
        uint2 st;
        st.x = pk2(Yt[eb][4 * g + 0] * rl, Yt[eb][4 * g + 1] * rl);
        st.y = pk2(Yt[eb][4 * g + 2] * rl, Yt[eb][4 * g + 3] * rl);
        *(uint2*)(yp + eb * 32 + g * 8) = st;
      }
  }
}

// ---------------- launch -----------------------------------------------------
extern "C" void kernel_launch(void* const* d_in, const int* in_sizes, int n_in,
                              void* d_out, int out_size, void* d_ws, size_t ws_size,
                              hipStream_t stream) {
  const float* x = (const float*)d_in[0];
  const float* kc = (const float*)d_in[1];
  const float* vc = (const float*)d_in[2];
  const float* Wqkv = (const float*)d_in[3];
  const float* bqkv = (const float*)d_in[4];
  const float* Wproj = (const float*)d_in[5];
  const float* bproj = (const float*)d_in[6];
  float* out = (float*)d_out;

  u16* qh = (u16*)d_ws;                  // 4194304
  u16* y2 = qh + 4194304;                // 4194304 (also scratch for new-v rows)
  u16* xb = y2 + 4194304;                // 4194304
  u16* WqT = xb + 4194304;               // 3145728
  u16* WpT = WqT + 3145728;              // 1048576
  u16* Km = WpT + 1048576;               // 20971520
  u16* Vtm = Km + 20971520;              // 20971520

  convert_f32_bf16<<<dim3(2048), 256, 0, stream>>>(x, xb);
  transpose_f32_bf16<<<dim3(48, 16), 256, 0, stream>>>(Wqkv, WqT, 1024, 3072);
  transpose_f32_bf16<<<dim3(16, 16), 256, 0, stream>>>(Wproj, WpT, 1024, 1024);
  prep_kv<<<dim3(128 * 32), 256, 0, stream>>>(kc, vc, Km, Vtm);

  // qkv = x @ Wqkv + bqkv -> qh (xQSCALE), Km[:, L:], v rows -> y2 scratch
  gemm128<0><<<dim3(24, 32), 256, 0, stream>>>(xb, WqT, bqkv, qh, Km, y2, nullptr,
                                               4096, 3072, 1024);
  vtrans<<<dim3(128 * 8), 256, 0, stream>>>(y2, Vtm);

  attn_v6<<<dim3(512), 512, 0, stream>>>(qh, Km, Vtm, y2);

  // out = y @ Wproj + bproj (f32 out)
  gemm128<1><<<dim3(8, 32), 256, 0, stream>>>(y2, WpT, bproj, nullptr, nullptr,
                                              nullptr, out, 4096, 1024, 1024);
}